// Round 14
// baseline (179.603 us; speedup 1.0000x reference)
//
#include <hip/hip_runtime.h>
#include <math.h>

// Problem constants (fixed by setup_inputs): N src points, M targets, D=3.
constexpr int N_SRC = 16384;
constexpr int M_TAR = 16384;

// R19: SIMT-ize the grid traversal. R18's counters: busy-time 24.6us ==
// brute force's, because the 27-cell ring/prune arithmetic ran wave-
// uniformly (64x redundant): ~810 of ~1000 wave-instrs/target were
// traversal logic, not point math; plus ~27 serial L2 trips/target at
// Occ 23% -> dur/busy = 3.3x. Fix:
//  - lane k<27 OWNS neighbor cell k: one gather loads all 27 cnt[] (1 L2
//    trip), one ~30-op sequence computes all 27 AABB lower bounds.
//  - scan home cell coalesced -> reduce best -> ballot(dlb<=thr) -> walk
//    the 2-4 surviving cells (uniform mask walk, __shfl broadcasts).
//  - early-exit if best beats the 3^3-box boundary distance (grid-edge
//    faces excluded: edge cells absorb overflow, nothing lies beyond).
//  - rare residue (~0.2%: empty neighborhoods / tail targets) falls into
//    the R18 ring loop from R=2 -- identical validated margin logic.
// ~190 wave-instrs and ~5 L2 trips per target (both ~5x less than R18).
// TPB=256 -> 8 blocks/CU = 32 waves/CU residency; small blocks shrink the
// straggler quantum. Build kernels unchanged (validated, invisible).

constexpr int   G     = 16;
constexpr int   NCELL = G * G * G;        // 4096
constexpr float GLO   = -4.0f;            // grid origin
constexpr float H     = 0.5f;             // cell size
constexpr float INVH  = 2.0f;
constexpr int   K     = 256;              // bucket capacity (max cell ~130)
constexpr int   PTS_CAP = NCELL * K + 16384;  // slack: no OOB ever

constexpr int TPB4    = 256;              // 4 waves = 4 targets per block
constexpr int TGTPB   = TPB4 / 64;
constexpr int BLOCKS4 = M_TAR / TGTPB;    // 4096 blocks

__device__ __forceinline__ int cell_of(float v) {
    int c = (int)floorf((v - GLO) * INVH);
    return min(max(c, 0), G - 1);          // edge cells absorb overflow
}

// ---- build stage 1: zero the 4096 counters (+ the output accumulator)
__global__ void zero_cnt(int* __restrict__ cnt, float* __restrict__ out) {
    int i = blockIdx.x * blockDim.x + threadIdx.x;
    if (i < NCELL) cnt[i] = 0;
    if (i == 0) out[0] = 0.0f;             // d_out poisoned 0xAA each launch
}

// ---- build stage 2: scatter points into fixed-capacity cell buckets
__global__ void scatter(const float* __restrict__ src,
                        int* __restrict__ cnt,
                        float4* __restrict__ pts) {
    int i = blockIdx.x * blockDim.x + threadIdx.x;   // 16384 threads exact
    const float* q = src + 3 * i;
    float x = q[0], y = q[1], z = q[2];
    int cid = (cell_of(z) * G + cell_of(y)) * G + cell_of(x);
    int pos = atomicAdd(&cnt[cid], 1);
    int idx = cid * K + pos;
    if (idx >= PTS_CAP) idx = PTS_CAP - 1; // unreachable; fault insurance
    pts[idx] = make_float4(x, y, z, 0.0f);
}

// ---- search: one wave per target; lane-parallel 27-cell neighborhood.
__global__ __launch_bounds__(TPB4, 8)
void nn_grid3(const int* __restrict__ cnt,
              const float4* __restrict__ pts,
              const float* __restrict__ tar,
              float* __restrict__ out) {
    __shared__ float term[TGTPB];
    const int tid  = threadIdx.x;
    const int wid  = tid >> 6;
    const int lane = tid & 63;

    const int T = blockIdx.x * TGTPB + wid;
    const float tx = tar[3 * T + 0], ty = tar[3 * T + 1], tz = tar[3 * T + 2];
    const int cx = cell_of(tx), cy = cell_of(ty), cz = cell_of(tz);

    // lane k<27 owns neighbor cell k = (oz+1)*9 + (oy+1)*3 + (ox+1)
    const int k  = lane;
    const int nx = cx + (k % 3) - 1;
    const int ny = cy + ((k / 3) % 3) - 1;
    const int nz = cz + (k / 9) - 1;
    const bool inb = (k < 27) && (unsigned)nx < (unsigned)G &&
                     (unsigned)ny < (unsigned)G && (unsigned)nz < (unsigned)G;
    const int cid    = (nz * G + ny) * G + nx;
    int n_k = 0;
    if (inb) n_k = cnt[cid];               // 27-lane gather: ONE L2 trip
    const int base_k = cid * K;

    // per-lane AABB lower bound (edge cells extended to +/-inf)
    float dlb = 1e30f;
    if (inb) {
        float lox = (nx == 0)     ? -1e30f : GLO + nx * H;
        float hix = (nx == G - 1) ?  1e30f : GLO + (nx + 1) * H;
        float loy = (ny == 0)     ? -1e30f : GLO + ny * H;
        float hiy = (ny == G - 1) ?  1e30f : GLO + (ny + 1) * H;
        float loz = (nz == 0)     ? -1e30f : GLO + nz * H;
        float hiz = (nz == G - 1) ?  1e30f : GLO + (nz + 1) * H;
        float ddx = tx - fminf(fmaxf(tx, lox), hix);
        float ddy = ty - fminf(fmaxf(ty, loy), hiy);
        float ddz = tz - fminf(fmaxf(tz, loz), hiz);
        dlb = fmaf(ddx, ddx, fmaf(ddy, ddy, ddz * ddz));
    }

    float best = 1e30f;

    // home cell (k=13) scan: coalesced 64-lane sweep
    {
        int nh = __shfl(n_k, 13, 64);
        int bh = __shfl(base_k, 13, 64);
        for (int j = lane; j < nh; j += 64) {
            float4 p = pts[bh + j];
            float dx = p.x - tx, dy = p.y - ty, dz = p.z - tz;
            best = fminf(best, fmaf(dx, dx, fmaf(dy, dy, dz * dz)));
        }
    }
#pragma unroll
    for (int s = 32; s >= 1; s >>= 1)
        best = fminf(best, __shfl_xor(best, s, 64));

    // lane-parallel prune of the 26 remaining cells; walk the survivors
    {
        float thr = fmaf(best, 1.0001f, 1e-6f);
        bool survive = inb && (k != 13) && (n_k > 0) && (dlb <= thr);
        unsigned long long mask = __ballot(survive);   // wave-uniform
        while (mask) {
            int c = __builtin_ctzll(mask);
            mask &= mask - 1;
            int n = __shfl(n_k, c, 64);
            int b = __shfl(base_k, c, 64);
            for (int j = lane; j < n; j += 64) {
                float4 p = pts[b + j];
                float dx = p.x - tx, dy = p.y - ty, dz = p.z - tz;
                best = fminf(best, fmaf(dx, dx, fmaf(dy, dy, dz * dz)));
            }
        }
    }
#pragma unroll
    for (int s = 32; s >= 1; s >>= 1)
        best = fminf(best, __shfl_xor(best, s, 64));

    // stop test: distance to the 3^3 box faces (grid-edge faces excluded)
    float dmin = 1e30f;
    if (cx - 1 > 0)     dmin = fminf(dmin, tx - (GLO + (cx - 1) * H));
    if (cx + 1 < G - 1) dmin = fminf(dmin, (GLO + (cx + 2) * H) - tx);
    if (cy - 1 > 0)     dmin = fminf(dmin, ty - (GLO + (cy - 1) * H));
    if (cy + 1 < G - 1) dmin = fminf(dmin, (GLO + (cy + 2) * H) - ty);
    if (cz - 1 > 0)     dmin = fminf(dmin, tz - (GLO + (cz - 1) * H));
    if (cz + 1 < G - 1) dmin = fminf(dmin, (GLO + (cz + 2) * H) - tz);
    bool done = (dmin > 9e29f) || (dmin * dmin > fmaf(best, 1.0001f, 1e-6f));

    if (!done) {
        // rare path (~0.2% of targets): R18's validated ring machinery, R>=2
        for (int R = 2; R < G; ++R) {
            const float thr = fmaf(best, 1.0001f, 1e-6f);
            const int zlo = max(cz - R, 0), zhi = min(cz + R, G - 1);
            const int ylo = max(cy - R, 0), yhi = min(cy + R, G - 1);
            const int xlo = max(cx - R, 0), xhi = min(cx + R, G - 1);
            for (int qz = zlo; qz <= zhi; ++qz) {
                int az = qz - cz; az = az < 0 ? -az : az;
                for (int qy = ylo; qy <= yhi; ++qy) {
                    int ay = qy - cy; ay = ay < 0 ? -ay : ay;
                    for (int qx = xlo; qx <= xhi; ++qx) {
                        int ax = qx - cx; ax = ax < 0 ? -ax : ax;
                        if (max(ax, max(ay, az)) != R) continue;
                        float lox = (qx == 0)     ? -1e30f : GLO + qx * H;
                        float hix = (qx == G - 1) ?  1e30f : GLO + (qx + 1) * H;
                        float loy = (qy == 0)     ? -1e30f : GLO + qy * H;
                        float hiy = (qy == G - 1) ?  1e30f : GLO + (qy + 1) * H;
                        float loz = (qz == 0)     ? -1e30f : GLO + qz * H;
                        float hiz = (qz == G - 1) ?  1e30f : GLO + (qz + 1) * H;
                        float ddx = tx - fminf(fmaxf(tx, lox), hix);
                        float ddy = ty - fminf(fmaxf(ty, loy), hiy);
                        float ddz = tz - fminf(fmaxf(tz, loz), hiz);
                        float dlb2 = fmaf(ddx, ddx, fmaf(ddy, ddy, ddz * ddz));
                        if (dlb2 > thr) continue;
                        int cid2 = (qz * G + qy) * G + qx;
                        int n = cnt[cid2];
                        int b = cid2 * K;
                        for (int j = lane; j < n; j += 64) {
                            float4 p = pts[b + j];
                            float dx = p.x - tx, dy = p.y - ty, dz = p.z - tz;
                            best = fminf(best, fmaf(dx, dx, fmaf(dy, dy, dz * dz)));
                        }
                    }
                }
            }
#pragma unroll
            for (int s = 32; s >= 1; s >>= 1)
                best = fminf(best, __shfl_xor(best, s, 64));
            float dm = 1e30f;
            if (cx - R > 0)     dm = fminf(dm, tx - (GLO + (cx - R) * H));
            if (cx + R < G - 1) dm = fminf(dm, (GLO + (cx + R + 1) * H) - tx);
            if (cy - R > 0)     dm = fminf(dm, ty - (GLO + (cy - R) * H));
            if (cy + R < G - 1) dm = fminf(dm, (GLO + (cy + R + 1) * H) - ty);
            if (cz - R > 0)     dm = fminf(dm, tz - (GLO + (cz - R) * H));
            if (cz + R < G - 1) dm = fminf(dm, (GLO + (cz + R + 1) * H) - tz);
            if (dm > 9e29f) break;
            if (dm * dm > fmaf(best, 1.0001f, 1e-6f)) break;
        }
    }

    if (lane == 0) term[wid] = 0.5f * best;   // loss term, diff form
    __syncthreads();
    if (tid == 0) {
        float s = 0.0f;
#pragma unroll
        for (int i = 0; i < TGTPB; ++i) s += term[i];
        atomicAdd(out, s);   // device-scope, cross-XCD safe
    }
}

extern "C" void kernel_launch(void* const* d_in, const int* in_sizes, int n_in,
                              void* d_out, int out_size, void* d_ws, size_t ws_size,
                              hipStream_t stream) {
    const float* src = (const float*)d_in[0];  // src_V [N,3] fp32
    const float* tar = (const float*)d_in[1];  // tar_V [M,3] fp32
    float* out = (float*)d_out;                // scalar loss fp32
    int*    cnt = (int*)d_ws;                              // 4096 ints
    float4* pts = (float4*)((char*)d_ws + 65536);          // NCELL*K + slack
    (void)ws_size;

    zero_cnt<<<4, 1024, 0, stream>>>(cnt, out);
    scatter<<<N_SRC / 1024, 1024, 0, stream>>>(src, cnt, pts);
    nn_grid3<<<BLOCKS4, TPB4, 0, stream>>>(cnt, pts, tar, out);
}

// Round 15
// 153.652 us; speedup vs baseline: 1.1689x; 1.1689x over previous
//
#include <hip/hip_runtime.h>
#include <math.h>

// Problem constants (fixed by setup_inputs): N src points, M targets, D=3.
constexpr int N_SRC = 16384;
constexpr int M_TAR = 16384;

// R20: R19's SIMT traversal (busy-time 7.9us, the predicted 5x cut) minus
// its two measured diseases:
//  (1) SPILLS: launch_bounds(256,8) + the inlined R>=2 ring fallback drove
//      the allocator to VGPR=32 and 2.3MB of scratch WRITE traffic in the
//      critical chain. Fix: the cold path is now a SEPARATE kernel
//      (nn_cold, R18's validated ring machinery verbatim, ~0.1-1% of
//      targets via an unresolved list); hot kernel live set ~30 regs,
//      launch_bounds(256,4) gives the allocator room (R10 precedent).
//  (2) ATOMIC DRAIN: 4096 same-address fp32 atomicAdds serialize at one
//      L2 line (~85-140us at the cold clock) -- likely THE R19 regression.
//      Fix: blocks add into 64 partials spread 128B apart (parallel RMW,
//      <=64 ops/address); a 64-thread finish kernel sums them into out.
// Traversal/prune/stop math identical to the absmax=0-validated R18/R19.

constexpr int   G     = 16;
constexpr int   NCELL = G * G * G;        // 4096
constexpr float GLO   = -4.0f;            // grid origin
constexpr float H     = 0.5f;             // cell size
constexpr float INVH  = 2.0f;
constexpr int   K     = 256;              // bucket capacity (max cell ~130)
constexpr int   PTS_CAP = NCELL * K + 16384;  // slack: no OOB ever

constexpr int TPB4    = 256;              // hot: 4 waves = 4 targets/block
constexpr int TGTPB   = TPB4 / 64;
constexpr int BLOCKS4 = M_TAR / TGTPB;    // 4096 blocks
constexpr int NPART   = 64;               // partial accumulators (x32 floats)

__device__ __forceinline__ int cell_of(float v) {
    int c = (int)floorf((v - GLO) * INVH);
    return min(max(c, 0), G - 1);          // edge cells absorb overflow
}

// ---- zero counters / unresolved count / partials (out written by finish)
__global__ void zero_ws(int* __restrict__ cnt, int* __restrict__ ucnt,
                        float* __restrict__ partials) {
    int i = blockIdx.x * blockDim.x + threadIdx.x;   // 4 x 1024
    if (i < NCELL) cnt[i] = 0;
    if (i == 0) ucnt[0] = 0;
    if (i < NPART) partials[i * 32] = 0.0f;
}

// ---- scatter points into fixed-capacity cell buckets
__global__ void scatter(const float* __restrict__ src,
                        int* __restrict__ cnt,
                        float4* __restrict__ pts) {
    int i = blockIdx.x * blockDim.x + threadIdx.x;   // 16384 threads exact
    const float* q = src + 3 * i;
    float x = q[0], y = q[1], z = q[2];
    int cid = (cell_of(z) * G + cell_of(y)) * G + cell_of(x);
    int pos = atomicAdd(&cnt[cid], 1);
    int idx = cid * K + pos;
    if (idx >= PTS_CAP) idx = PTS_CAP - 1; // unreachable; fault insurance
    pts[idx] = make_float4(x, y, z, 0.0f);
}

// ---- hot: one wave/target, lane-parallel 3^3 neighborhood, NO cold code.
__global__ __launch_bounds__(TPB4, 4)
void nn_hot(const int* __restrict__ cnt,
            const float4* __restrict__ pts,
            const float* __restrict__ tar,
            float* __restrict__ partials,
            int* __restrict__ ucnt,
            int* __restrict__ ulist) {
    __shared__ float term[TGTPB];
    const int tid  = threadIdx.x;
    const int wid  = tid >> 6;
    const int lane = tid & 63;

    const int T = blockIdx.x * TGTPB + wid;
    const float tx = tar[3 * T + 0], ty = tar[3 * T + 1], tz = tar[3 * T + 2];
    const int cx = cell_of(tx), cy = cell_of(ty), cz = cell_of(tz);

    // lane k<27 owns neighbor cell k = (oz+1)*9 + (oy+1)*3 + (ox+1)
    const int k  = lane;
    const int nx = cx + (k % 3) - 1;
    const int ny = cy + ((k / 3) % 3) - 1;
    const int nz = cz + (k / 9) - 1;
    const bool inb = (k < 27) && (unsigned)nx < (unsigned)G &&
                     (unsigned)ny < (unsigned)G && (unsigned)nz < (unsigned)G;
    const int cid = (nz * G + ny) * G + nx;
    int n_k = 0;
    if (inb) n_k = cnt[cid];               // 27-lane gather: ONE L2 trip
    const int base_k = cid * K;

    float dlb = 1e30f;                     // AABB lower bound (edge -> inf)
    if (inb) {
        float lox = (nx == 0)     ? -1e30f : GLO + nx * H;
        float hix = (nx == G - 1) ?  1e30f : GLO + (nx + 1) * H;
        float loy = (ny == 0)     ? -1e30f : GLO + ny * H;
        float hiy = (ny == G - 1) ?  1e30f : GLO + (ny + 1) * H;
        float loz = (nz == 0)     ? -1e30f : GLO + nz * H;
        float hiz = (nz == G - 1) ?  1e30f : GLO + (nz + 1) * H;
        float ddx = tx - fminf(fmaxf(tx, lox), hix);
        float ddy = ty - fminf(fmaxf(ty, loy), hiy);
        float ddz = tz - fminf(fmaxf(tz, loz), hiz);
        dlb = fmaf(ddx, ddx, fmaf(ddy, ddy, ddz * ddz));
    }

    float best = 1e30f;
    {   // home cell (k=13): coalesced 64-lane sweep
        int nh = __shfl(n_k, 13, 64);
        int bh = __shfl(base_k, 13, 64);
        for (int j = lane; j < nh; j += 64) {
            float4 p = pts[bh + j];
            float dx = p.x - tx, dy = p.y - ty, dz = p.z - tz;
            best = fminf(best, fmaf(dx, dx, fmaf(dy, dy, dz * dz)));
        }
    }
#pragma unroll
    for (int s = 32; s >= 1; s >>= 1)
        best = fminf(best, __shfl_xor(best, s, 64));

    {   // lane-parallel prune; walk surviving cells
        float thr = fmaf(best, 1.0001f, 1e-6f);
        bool survive = inb && (k != 13) && (n_k > 0) && (dlb <= thr);
        unsigned long long mask = __ballot(survive);   // wave-uniform
        while (mask) {
            int c = __builtin_ctzll(mask);
            mask &= mask - 1;
            int n = __shfl(n_k, c, 64);
            int b = __shfl(base_k, c, 64);
            for (int j = lane; j < n; j += 64) {
                float4 p = pts[b + j];
                float dx = p.x - tx, dy = p.y - ty, dz = p.z - tz;
                best = fminf(best, fmaf(dx, dx, fmaf(dy, dy, dz * dz)));
            }
        }
    }
#pragma unroll
    for (int s = 32; s >= 1; s >>= 1)
        best = fminf(best, __shfl_xor(best, s, 64));

    // stop test: distance to the 3^3 box faces (grid-edge faces excluded)
    float dmin = 1e30f;
    if (cx - 1 > 0)     dmin = fminf(dmin, tx - (GLO + (cx - 1) * H));
    if (cx + 1 < G - 1) dmin = fminf(dmin, (GLO + (cx + 2) * H) - tx);
    if (cy - 1 > 0)     dmin = fminf(dmin, ty - (GLO + (cy - 1) * H));
    if (cy + 1 < G - 1) dmin = fminf(dmin, (GLO + (cy + 2) * H) - ty);
    if (cz - 1 > 0)     dmin = fminf(dmin, tz - (GLO + (cz - 1) * H));
    if (cz + 1 < G - 1) dmin = fminf(dmin, (GLO + (cz + 2) * H) - tz);
    bool done = (dmin > 9e29f) || (dmin * dmin > fmaf(best, 1.0001f, 1e-6f));

    if (lane == 0) {
        term[wid] = done ? 0.5f * best : 0.0f;   // unresolved: cold adds it
        if (!done) {
            int slot = atomicAdd(ucnt, 1);
            ulist[slot] = T;
        }
    }
    __syncthreads();
    if (tid == 0) {
        float s = term[0] + term[1] + term[2] + term[3];
        atomicAdd(&partials[(blockIdx.x & (NPART - 1)) * 32], s);
    }
}

// ---- cold: R18's validated full ring machinery for unresolved targets.
__global__ __launch_bounds__(256, 2)
void nn_cold(const int* __restrict__ cnt,
             const float4* __restrict__ pts,
             const float* __restrict__ tar,
             const int* __restrict__ ucnt,
             const int* __restrict__ ulist,
             float* __restrict__ partials) {
    const int lane = threadIdx.x & 63;
    const int gw   = (blockIdx.x * blockDim.x + threadIdx.x) >> 6;
    const int nw   = (gridDim.x * blockDim.x) >> 6;
    const int nu   = ucnt[0];
    float acc = 0.0f;
    for (int u = gw; u < nu; u += nw) {
        const int T = ulist[u];
        const float tx = tar[3 * T + 0], ty = tar[3 * T + 1], tz = tar[3 * T + 2];
        const int cx = cell_of(tx), cy = cell_of(ty), cz = cell_of(tz);
        float best = 1e30f;
        for (int R = 0; R < G; ++R) {
            const float thr = fmaf(best, 1.0001f, 1e-6f);
            const int zlo = max(cz - R, 0), zhi = min(cz + R, G - 1);
            const int ylo = max(cy - R, 0), yhi = min(cy + R, G - 1);
            const int xlo = max(cx - R, 0), xhi = min(cx + R, G - 1);
            for (int qz = zlo; qz <= zhi; ++qz) {
                int az = qz - cz; az = az < 0 ? -az : az;
                for (int qy = ylo; qy <= yhi; ++qy) {
                    int ay = qy - cy; ay = ay < 0 ? -ay : ay;
                    for (int qx = xlo; qx <= xhi; ++qx) {
                        int ax = qx - cx; ax = ax < 0 ? -ax : ax;
                        if (max(ax, max(ay, az)) != R) continue;
                        float lox = (qx == 0)     ? -1e30f : GLO + qx * H;
                        float hix = (qx == G - 1) ?  1e30f : GLO + (qx + 1) * H;
                        float loy = (qy == 0)     ? -1e30f : GLO + qy * H;
                        float hiy = (qy == G - 1) ?  1e30f : GLO + (qy + 1) * H;
                        float loz = (qz == 0)     ? -1e30f : GLO + qz * H;
                        float hiz = (qz == G - 1) ?  1e30f : GLO + (qz + 1) * H;
                        float ddx = tx - fminf(fmaxf(tx, lox), hix);
                        float ddy = ty - fminf(fmaxf(ty, loy), hiy);
                        float ddz = tz - fminf(fmaxf(tz, loz), hiz);
                        float dlb = fmaf(ddx, ddx, fmaf(ddy, ddy, ddz * ddz));
                        if (dlb > thr) continue;
                        int cid = (qz * G + qy) * G + qx;
                        int n = cnt[cid];
                        int b = cid * K;
                        for (int j = lane; j < n; j += 64) {
                            float4 p = pts[b + j];
                            float dx = p.x - tx, dy = p.y - ty, dz = p.z - tz;
                            best = fminf(best, fmaf(dx, dx, fmaf(dy, dy, dz * dz)));
                        }
                    }
                }
            }
#pragma unroll
            for (int s = 32; s >= 1; s >>= 1)
                best = fminf(best, __shfl_xor(best, s, 64));
            float dm = 1e30f;
            if (cx - R > 0)     dm = fminf(dm, tx - (GLO + (cx - R) * H));
            if (cx + R < G - 1) dm = fminf(dm, (GLO + (cx + R + 1) * H) - tx);
            if (cy - R > 0)     dm = fminf(dm, ty - (GLO + (cy - R) * H));
            if (cy + R < G - 1) dm = fminf(dm, (GLO + (cy + R + 1) * H) - ty);
            if (cz - R > 0)     dm = fminf(dm, tz - (GLO + (cz - R) * H));
            if (cz + R < G - 1) dm = fminf(dm, (GLO + (cz + R + 1) * H) - tz);
            if (dm > 9e29f) break;
            if (dm * dm > fmaf(best, 1.0001f, 1e-6f)) break;
        }
        acc += 0.5f * best;
    }
    if (lane == 0 && acc > 0.0f)
        atomicAdd(&partials[(gw & (NPART - 1)) * 32], acc);
}

// ---- finish: sum the 64 partials, write the scalar (overwrites poison)
__global__ void finish(const float* __restrict__ partials,
                       float* __restrict__ out) {
    float v = partials[threadIdx.x * 32];   // 64 threads
#pragma unroll
    for (int s = 32; s >= 1; s >>= 1) v += __shfl_xor(v, s, 64);
    if (threadIdx.x == 0) out[0] = v;
}

extern "C" void kernel_launch(void* const* d_in, const int* in_sizes, int n_in,
                              void* d_out, int out_size, void* d_ws, size_t ws_size,
                              hipStream_t stream) {
    const float* src = (const float*)d_in[0];  // src_V [N,3] fp32
    const float* tar = (const float*)d_in[1];  // tar_V [M,3] fp32
    float* out = (float*)d_out;                // scalar loss fp32
    char* ws = (char*)d_ws;
    int*    cnt      = (int*)(ws + 0);         // 4096 ints (16 KB)
    int*    ucnt     = (int*)(ws + 16384);     // 1 int
    float*  partials = (float*)(ws + 20480);   // 64 x stride-32 floats (8 KB)
    int*    ulist    = (int*)(ws + 32768);     // 16384 ints (64 KB)
    float4* pts      = (float4*)(ws + 131072); // NCELL*K + slack
    (void)ws_size;

    zero_ws<<<4, 1024, 0, stream>>>(cnt, ucnt, partials);
    scatter<<<N_SRC / 1024, 1024, 0, stream>>>(src, cnt, pts);
    nn_hot<<<BLOCKS4, TPB4, 0, stream>>>(cnt, pts, tar, partials, ucnt, ulist);
    nn_cold<<<64, 256, 0, stream>>>(cnt, pts, tar, ucnt, ulist, partials);
    finish<<<1, 64, 0, stream>>>(partials, out);
}

// Round 16
// 122.755 us; speedup vs baseline: 1.4631x; 1.2517x over previous
//
#include <hip/hip_runtime.h>
#include <math.h>

// Problem constants (fixed by setup_inputs): N src points, M targets, D=3.
constexpr int N_SRC = 16384;
constexpr int M_TAR = 16384;

// R21: replace the cold path with brute force. R20's profile: nn_cold =
// 83.7us at VALUBusy 0.4% / Occ 0.2% -- a few straggler waves running the
// ring machinery serially in its worst regime (far-tail targets, shells of
// 300-1300 cells, AABB math wave-uniform = 64x redundant, ~50us per deep
// target at the cold clock). For the ~100-400 unresolved targets, an exact
// 64-lane coalesced scan of ALL 16384 raw src points costs ~5us per wave,
// and 1024 grid-striding waves do them all in parallel: total ~5us, fully
// uniform control flow, trivially exact. Ring logic deleted from runtime.
// zero_ws / scatter / nn_hot / finish are byte-identical to R20 (validated
// absmax=0; hot ~20us by subtraction, attacked next round).

constexpr int   G     = 16;
constexpr int   NCELL = G * G * G;        // 4096
constexpr float GLO   = -4.0f;            // grid origin
constexpr float H     = 0.5f;             // cell size
constexpr float INVH  = 2.0f;
constexpr int   K     = 256;              // bucket capacity (max cell ~130)
constexpr int   PTS_CAP = NCELL * K + 16384;  // slack: no OOB ever

constexpr int TPB4    = 256;              // hot: 4 waves = 4 targets/block
constexpr int TGTPB   = TPB4 / 64;
constexpr int BLOCKS4 = M_TAR / TGTPB;    // 4096 blocks
constexpr int NPART   = 64;               // partial accumulators (x32 floats)

__device__ __forceinline__ int cell_of(float v) {
    int c = (int)floorf((v - GLO) * INVH);
    return min(max(c, 0), G - 1);          // edge cells absorb overflow
}

// ---- zero counters / unresolved count / partials (out written by finish)
__global__ void zero_ws(int* __restrict__ cnt, int* __restrict__ ucnt,
                        float* __restrict__ partials) {
    int i = blockIdx.x * blockDim.x + threadIdx.x;   // 4 x 1024
    if (i < NCELL) cnt[i] = 0;
    if (i == 0) ucnt[0] = 0;
    if (i < NPART) partials[i * 32] = 0.0f;
}

// ---- scatter points into fixed-capacity cell buckets
__global__ void scatter(const float* __restrict__ src,
                        int* __restrict__ cnt,
                        float4* __restrict__ pts) {
    int i = blockIdx.x * blockDim.x + threadIdx.x;   // 16384 threads exact
    const float* q = src + 3 * i;
    float x = q[0], y = q[1], z = q[2];
    int cid = (cell_of(z) * G + cell_of(y)) * G + cell_of(x);
    int pos = atomicAdd(&cnt[cid], 1);
    int idx = cid * K + pos;
    if (idx >= PTS_CAP) idx = PTS_CAP - 1; // unreachable; fault insurance
    pts[idx] = make_float4(x, y, z, 0.0f);
}

// ---- hot: one wave/target, lane-parallel 3^3 neighborhood (R20 verbatim).
__global__ __launch_bounds__(TPB4, 4)
void nn_hot(const int* __restrict__ cnt,
            const float4* __restrict__ pts,
            const float* __restrict__ tar,
            float* __restrict__ partials,
            int* __restrict__ ucnt,
            int* __restrict__ ulist) {
    __shared__ float term[TGTPB];
    const int tid  = threadIdx.x;
    const int wid  = tid >> 6;
    const int lane = tid & 63;

    const int T = blockIdx.x * TGTPB + wid;
    const float tx = tar[3 * T + 0], ty = tar[3 * T + 1], tz = tar[3 * T + 2];
    const int cx = cell_of(tx), cy = cell_of(ty), cz = cell_of(tz);

    // lane k<27 owns neighbor cell k = (oz+1)*9 + (oy+1)*3 + (ox+1)
    const int k  = lane;
    const int nx = cx + (k % 3) - 1;
    const int ny = cy + ((k / 3) % 3) - 1;
    const int nz = cz + (k / 9) - 1;
    const bool inb = (k < 27) && (unsigned)nx < (unsigned)G &&
                     (unsigned)ny < (unsigned)G && (unsigned)nz < (unsigned)G;
    const int cid = (nz * G + ny) * G + nx;
    int n_k = 0;
    if (inb) n_k = cnt[cid];               // 27-lane gather: ONE L2 trip
    const int base_k = cid * K;

    float dlb = 1e30f;                     // AABB lower bound (edge -> inf)
    if (inb) {
        float lox = (nx == 0)     ? -1e30f : GLO + nx * H;
        float hix = (nx == G - 1) ?  1e30f : GLO + (nx + 1) * H;
        float loy = (ny == 0)     ? -1e30f : GLO + ny * H;
        float hiy = (ny == G - 1) ?  1e30f : GLO + (ny + 1) * H;
        float loz = (nz == 0)     ? -1e30f : GLO + nz * H;
        float hiz = (nz == G - 1) ?  1e30f : GLO + (nz + 1) * H;
        float ddx = tx - fminf(fmaxf(tx, lox), hix);
        float ddy = ty - fminf(fmaxf(ty, loy), hiy);
        float ddz = tz - fminf(fmaxf(tz, loz), hiz);
        dlb = fmaf(ddx, ddx, fmaf(ddy, ddy, ddz * ddz));
    }

    float best = 1e30f;
    {   // home cell (k=13): coalesced 64-lane sweep
        int nh = __shfl(n_k, 13, 64);
        int bh = __shfl(base_k, 13, 64);
        for (int j = lane; j < nh; j += 64) {
            float4 p = pts[bh + j];
            float dx = p.x - tx, dy = p.y - ty, dz = p.z - tz;
            best = fminf(best, fmaf(dx, dx, fmaf(dy, dy, dz * dz)));
        }
    }
#pragma unroll
    for (int s = 32; s >= 1; s >>= 1)
        best = fminf(best, __shfl_xor(best, s, 64));

    {   // lane-parallel prune; walk surviving cells
        float thr = fmaf(best, 1.0001f, 1e-6f);
        bool survive = inb && (k != 13) && (n_k > 0) && (dlb <= thr);
        unsigned long long mask = __ballot(survive);   // wave-uniform
        while (mask) {
            int c = __builtin_ctzll(mask);
            mask &= mask - 1;
            int n = __shfl(n_k, c, 64);
            int b = __shfl(base_k, c, 64);
            for (int j = lane; j < n; j += 64) {
                float4 p = pts[b + j];
                float dx = p.x - tx, dy = p.y - ty, dz = p.z - tz;
                best = fminf(best, fmaf(dx, dx, fmaf(dy, dy, dz * dz)));
            }
        }
    }
#pragma unroll
    for (int s = 32; s >= 1; s >>= 1)
        best = fminf(best, __shfl_xor(best, s, 64));

    // stop test: distance to the 3^3 box faces (grid-edge faces excluded)
    float dmin = 1e30f;
    if (cx - 1 > 0)     dmin = fminf(dmin, tx - (GLO + (cx - 1) * H));
    if (cx + 1 < G - 1) dmin = fminf(dmin, (GLO + (cx + 2) * H) - tx);
    if (cy - 1 > 0)     dmin = fminf(dmin, ty - (GLO + (cy - 1) * H));
    if (cy + 1 < G - 1) dmin = fminf(dmin, (GLO + (cy + 2) * H) - ty);
    if (cz - 1 > 0)     dmin = fminf(dmin, tz - (GLO + (cz - 1) * H));
    if (cz + 1 < G - 1) dmin = fminf(dmin, (GLO + (cz + 2) * H) - tz);
    bool done = (dmin > 9e29f) || (dmin * dmin > fmaf(best, 1.0001f, 1e-6f));

    if (lane == 0) {
        term[wid] = done ? 0.5f * best : 0.0f;   // unresolved: cold adds it
        if (!done) {
            int slot = atomicAdd(ucnt, 1);
            ulist[slot] = T;
        }
    }
    __syncthreads();
    if (tid == 0) {
        float s = term[0] + term[1] + term[2] + term[3];
        atomicAdd(&partials[(blockIdx.x & (NPART - 1)) * 32], s);
    }
}

// ---- cold: brute-force exact scan, one wave per unresolved target.
// Uniform control flow, coalesced reads of raw src, ~5us for all targets.
__global__ __launch_bounds__(256, 4)
void nn_cold(const float* __restrict__ src,
             const float* __restrict__ tar,
             const int* __restrict__ ucnt,
             const int* __restrict__ ulist,
             float* __restrict__ partials) {
    const int lane = threadIdx.x & 63;
    const int gw   = (blockIdx.x * blockDim.x + threadIdx.x) >> 6;
    const int nw   = (gridDim.x * blockDim.x) >> 6;
    const int nu   = ucnt[0];
    float acc = 0.0f;
    for (int u = gw; u < nu; u += nw) {
        const int T = ulist[u];
        const float tx = tar[3 * T + 0], ty = tar[3 * T + 1], tz = tar[3 * T + 2];
        float best = 1e30f;
        for (int j = lane; j < N_SRC; j += 64) {   // 256 coalesced iters
            const float* q = src + 3 * j;
            float dx = q[0] - tx, dy = q[1] - ty, dz = q[2] - tz;
            best = fminf(best, fmaf(dx, dx, fmaf(dy, dy, dz * dz)));
        }
#pragma unroll
        for (int s = 32; s >= 1; s >>= 1)
            best = fminf(best, __shfl_xor(best, s, 64));
        if (lane == 0) acc += 0.5f * best;
    }
    if (lane == 0 && acc != 0.0f)
        atomicAdd(&partials[(gw & (NPART - 1)) * 32], acc);
}

// ---- finish: sum the 64 partials, write the scalar (overwrites poison)
__global__ void finish(const float* __restrict__ partials,
                       float* __restrict__ out) {
    float v = partials[threadIdx.x * 32];   // 64 threads
#pragma unroll
    for (int s = 32; s >= 1; s >>= 1) v += __shfl_xor(v, s, 64);
    if (threadIdx.x == 0) out[0] = v;
}

extern "C" void kernel_launch(void* const* d_in, const int* in_sizes, int n_in,
                              void* d_out, int out_size, void* d_ws, size_t ws_size,
                              hipStream_t stream) {
    const float* src = (const float*)d_in[0];  // src_V [N,3] fp32
    const float* tar = (const float*)d_in[1];  // tar_V [M,3] fp32
    float* out = (float*)d_out;                // scalar loss fp32
    char* ws = (char*)d_ws;
    int*    cnt      = (int*)(ws + 0);         // 4096 ints (16 KB)
    int*    ucnt     = (int*)(ws + 16384);     // 1 int
    float*  partials = (float*)(ws + 20480);   // 64 x stride-32 floats (8 KB)
    int*    ulist    = (int*)(ws + 32768);     // 16384 ints (64 KB)
    float4* pts      = (float4*)(ws + 131072); // NCELL*K + slack
    (void)ws_size;

    zero_ws<<<4, 1024, 0, stream>>>(cnt, ucnt, partials);
    scatter<<<N_SRC / 1024, 1024, 0, stream>>>(src, cnt, pts);
    nn_hot<<<BLOCKS4, TPB4, 0, stream>>>(cnt, pts, tar, partials, ucnt, ulist);
    nn_cold<<<256, 256, 0, stream>>>(src, tar, ucnt, ulist, partials);
    finish<<<1, 64, 0, stream>>>(partials, out);
}

// Round 17
// 85.806 us; speedup vs baseline: 2.0931x; 1.4306x over previous
//
#include <hip/hip_runtime.h>
#include <math.h>

// Problem constants (fixed by setup_inputs): N src points, M targets, D=3.
constexpr int N_SRC = 16384;
constexpr int M_TAR = 16384;

// R22: kill nn_cold's serial latency chain. R21 profile: nn_cold 49.2us at
// VALUBusy 0.6% / Occ 0.6% -- ~dozens of waves, EACH running 256 sequential
// load->fma iterations (~230cyc L2 latency apiece at the cold ~1.2GHz
// clock) with zero TLP. Busy-time was 0.3us; it's 100% latency.
// Fix: decompose cold work into (target, slice) pairs -- 16 slices x 1024
// points. Grid-stride over nu*16 work items with 2048 waves: per-wave
// chain drops to 16 iterations (~3us), parallelism rises ~16x. Publish
// per-target minima via atomicMin on float-as-uint (valid: d^2 >= 0, so
// uint order == float order); cold_sum adds 0.5*umin[T] into the partials.
// nn_hot / scatter / finish byte-identical to R21 (validated absmax=0);
// zero_ws additionally inits the umin array; pts moved up in ws.

constexpr int   G     = 16;
constexpr int   NCELL = G * G * G;        // 4096
constexpr float GLO   = -4.0f;            // grid origin
constexpr float H     = 0.5f;             // cell size
constexpr float INVH  = 2.0f;
constexpr int   K     = 256;              // bucket capacity (max cell ~130)
constexpr int   PTS_CAP = NCELL * K + 16384;  // slack: no OOB ever

constexpr int TPB4    = 256;              // hot: 4 waves = 4 targets/block
constexpr int TGTPB   = TPB4 / 64;
constexpr int BLOCKS4 = M_TAR / TGTPB;    // 4096 blocks
constexpr int NPART   = 64;               // partial accumulators (x32 floats)

constexpr int SLICES  = 16;               // cold: 1024-point slices
constexpr int SLICE_PTS = N_SRC / SLICES;

__device__ __forceinline__ int cell_of(float v) {
    int c = (int)floorf((v - GLO) * INVH);
    return min(max(c, 0), G - 1);          // edge cells absorb overflow
}

// ---- zero counters / unresolved count / partials / per-target minima
__global__ void zero_ws(int* __restrict__ cnt, int* __restrict__ ucnt,
                        float* __restrict__ partials,
                        unsigned int* __restrict__ umin) {
    int i = blockIdx.x * blockDim.x + threadIdx.x;   // 16 x 1024 = 16384
    if (i < NCELL) cnt[i] = 0;
    if (i == 0) ucnt[0] = 0;
    if (i < NPART) partials[i * 32] = 0.0f;
    umin[i] = 0x7F800000u;                 // +inf as uint
}

// ---- scatter points into fixed-capacity cell buckets
__global__ void scatter(const float* __restrict__ src,
                        int* __restrict__ cnt,
                        float4* __restrict__ pts) {
    int i = blockIdx.x * blockDim.x + threadIdx.x;   // 16384 threads exact
    const float* q = src + 3 * i;
    float x = q[0], y = q[1], z = q[2];
    int cid = (cell_of(z) * G + cell_of(y)) * G + cell_of(x);
    int pos = atomicAdd(&cnt[cid], 1);
    int idx = cid * K + pos;
    if (idx >= PTS_CAP) idx = PTS_CAP - 1; // unreachable; fault insurance
    pts[idx] = make_float4(x, y, z, 0.0f);
}

// ---- hot: one wave/target, lane-parallel 3^3 neighborhood (R21 verbatim).
__global__ __launch_bounds__(TPB4, 4)
void nn_hot(const int* __restrict__ cnt,
            const float4* __restrict__ pts,
            const float* __restrict__ tar,
            float* __restrict__ partials,
            int* __restrict__ ucnt,
            int* __restrict__ ulist) {
    __shared__ float term[TGTPB];
    const int tid  = threadIdx.x;
    const int wid  = tid >> 6;
    const int lane = tid & 63;

    const int T = blockIdx.x * TGTPB + wid;
    const float tx = tar[3 * T + 0], ty = tar[3 * T + 1], tz = tar[3 * T + 2];
    const int cx = cell_of(tx), cy = cell_of(ty), cz = cell_of(tz);

    // lane k<27 owns neighbor cell k = (oz+1)*9 + (oy+1)*3 + (ox+1)
    const int k  = lane;
    const int nx = cx + (k % 3) - 1;
    const int ny = cy + ((k / 3) % 3) - 1;
    const int nz = cz + (k / 9) - 1;
    const bool inb = (k < 27) && (unsigned)nx < (unsigned)G &&
                     (unsigned)ny < (unsigned)G && (unsigned)nz < (unsigned)G;
    const int cid = (nz * G + ny) * G + nx;
    int n_k = 0;
    if (inb) n_k = cnt[cid];               // 27-lane gather: ONE L2 trip
    const int base_k = cid * K;

    float dlb = 1e30f;                     // AABB lower bound (edge -> inf)
    if (inb) {
        float lox = (nx == 0)     ? -1e30f : GLO + nx * H;
        float hix = (nx == G - 1) ?  1e30f : GLO + (nx + 1) * H;
        float loy = (ny == 0)     ? -1e30f : GLO + ny * H;
        float hiy = (ny == G - 1) ?  1e30f : GLO + (ny + 1) * H;
        float loz = (nz == 0)     ? -1e30f : GLO + nz * H;
        float hiz = (nz == G - 1) ?  1e30f : GLO + (nz + 1) * H;
        float ddx = tx - fminf(fmaxf(tx, lox), hix);
        float ddy = ty - fminf(fmaxf(ty, loy), hiy);
        float ddz = tz - fminf(fmaxf(tz, loz), hiz);
        dlb = fmaf(ddx, ddx, fmaf(ddy, ddy, ddz * ddz));
    }

    float best = 1e30f;
    {   // home cell (k=13): coalesced 64-lane sweep
        int nh = __shfl(n_k, 13, 64);
        int bh = __shfl(base_k, 13, 64);
        for (int j = lane; j < nh; j += 64) {
            float4 p = pts[bh + j];
            float dx = p.x - tx, dy = p.y - ty, dz = p.z - tz;
            best = fminf(best, fmaf(dx, dx, fmaf(dy, dy, dz * dz)));
        }
    }
#pragma unroll
    for (int s = 32; s >= 1; s >>= 1)
        best = fminf(best, __shfl_xor(best, s, 64));

    {   // lane-parallel prune; walk surviving cells
        float thr = fmaf(best, 1.0001f, 1e-6f);
        bool survive = inb && (k != 13) && (n_k > 0) && (dlb <= thr);
        unsigned long long mask = __ballot(survive);   // wave-uniform
        while (mask) {
            int c = __builtin_ctzll(mask);
            mask &= mask - 1;
            int n = __shfl(n_k, c, 64);
            int b = __shfl(base_k, c, 64);
            for (int j = lane; j < n; j += 64) {
                float4 p = pts[b + j];
                float dx = p.x - tx, dy = p.y - ty, dz = p.z - tz;
                best = fminf(best, fmaf(dx, dx, fmaf(dy, dy, dz * dz)));
            }
        }
    }
#pragma unroll
    for (int s = 32; s >= 1; s >>= 1)
        best = fminf(best, __shfl_xor(best, s, 64));

    // stop test: distance to the 3^3 box faces (grid-edge faces excluded)
    float dmin = 1e30f;
    if (cx - 1 > 0)     dmin = fminf(dmin, tx - (GLO + (cx - 1) * H));
    if (cx + 1 < G - 1) dmin = fminf(dmin, (GLO + (cx + 2) * H) - tx);
    if (cy - 1 > 0)     dmin = fminf(dmin, ty - (GLO + (cy - 1) * H));
    if (cy + 1 < G - 1) dmin = fminf(dmin, (GLO + (cy + 2) * H) - ty);
    if (cz - 1 > 0)     dmin = fminf(dmin, tz - (GLO + (cz - 1) * H));
    if (cz + 1 < G - 1) dmin = fminf(dmin, (GLO + (cz + 2) * H) - tz);
    bool done = (dmin > 9e29f) || (dmin * dmin > fmaf(best, 1.0001f, 1e-6f));

    if (lane == 0) {
        term[wid] = done ? 0.5f * best : 0.0f;   // unresolved: cold adds it
        if (!done) {
            int slot = atomicAdd(ucnt, 1);
            ulist[slot] = T;
        }
    }
    __syncthreads();
    if (tid == 0) {
        float s = term[0] + term[1] + term[2] + term[3];
        atomicAdd(&partials[(blockIdx.x & (NPART - 1)) * 32], s);
    }
}

// ---- cold: (target, slice) grid-stride; 16-iteration chains, high TLP.
__global__ __launch_bounds__(256, 4)
void nn_cold(const float* __restrict__ src,
             const float* __restrict__ tar,
             const int* __restrict__ ucnt,
             const int* __restrict__ ulist,
             unsigned int* __restrict__ umin) {
    const int lane = threadIdx.x & 63;
    const int gw   = (blockIdx.x * blockDim.x + threadIdx.x) >> 6;
    const int nw   = (gridDim.x * blockDim.x) >> 6;
    const int work = ucnt[0] * SLICES;
    for (int w = gw; w < work; w += nw) {
        const int u     = w >> 4;          // / SLICES
        const int slice = w & (SLICES - 1);
        const int T = ulist[u];
        const float tx = tar[3 * T + 0], ty = tar[3 * T + 1], tz = tar[3 * T + 2];
        float best = 1e30f;
        const int jend = (slice + 1) * SLICE_PTS;
        for (int j = slice * SLICE_PTS + lane; j < jend; j += 64) {  // 16 it
            const float* q = src + 3 * j;
            float dx = q[0] - tx, dy = q[1] - ty, dz = q[2] - tz;
            best = fminf(best, fmaf(dx, dx, fmaf(dy, dy, dz * dz)));
        }
#pragma unroll
        for (int s = 32; s >= 1; s >>= 1)
            best = fminf(best, __shfl_xor(best, s, 64));
        if (lane == 0)
            atomicMin(&umin[T], __float_as_uint(best));  // d2>=0: uint==float order
    }
}

// ---- cold_sum: add the unresolved targets' minima into the partials
__global__ void cold_sum(const int* __restrict__ ucnt,
                         const int* __restrict__ ulist,
                         const unsigned int* __restrict__ umin,
                         float* __restrict__ partials) {
    const int tid = threadIdx.x;           // one block, 1024 threads
    const int nu  = ucnt[0];
    float acc = 0.0f;
    for (int u = tid; u < nu; u += 1024)
        acc += 0.5f * __uint_as_float(umin[ulist[u]]);
#pragma unroll
    for (int s = 32; s >= 1; s >>= 1) acc += __shfl_xor(acc, s, 64);
    if ((tid & 63) == 0 && acc != 0.0f)
        atomicAdd(&partials[(tid >> 6) * 32], acc);
}

// ---- finish: sum the 64 partials, write the scalar (overwrites poison)
__global__ void finish(const float* __restrict__ partials,
                       float* __restrict__ out) {
    float v = partials[threadIdx.x * 32];   // 64 threads
#pragma unroll
    for (int s = 32; s >= 1; s >>= 1) v += __shfl_xor(v, s, 64);
    if (threadIdx.x == 0) out[0] = v;
}

extern "C" void kernel_launch(void* const* d_in, const int* in_sizes, int n_in,
                              void* d_out, int out_size, void* d_ws, size_t ws_size,
                              hipStream_t stream) {
    const float* src = (const float*)d_in[0];  // src_V [N,3] fp32
    const float* tar = (const float*)d_in[1];  // tar_V [M,3] fp32
    float* out = (float*)d_out;                // scalar loss fp32
    char* ws = (char*)d_ws;
    int*          cnt      = (int*)(ws + 0);        // 4096 ints (16 KB)
    int*          ucnt     = (int*)(ws + 16384);    // 1 int
    float*        partials = (float*)(ws + 20480);  // 64 x stride-32 (8 KB)
    int*          ulist    = (int*)(ws + 32768);    // 16384 ints (64 KB)
    unsigned int* umin     = (unsigned int*)(ws + 98304);  // 16384 u32 (64 KB)
    float4*       pts      = (float4*)(ws + 196608);       // NCELL*K + slack
    (void)ws_size;

    zero_ws<<<16, 1024, 0, stream>>>(cnt, ucnt, partials, umin);
    scatter<<<N_SRC / 1024, 1024, 0, stream>>>(src, cnt, pts);
    nn_hot<<<BLOCKS4, TPB4, 0, stream>>>(cnt, pts, tar, partials, ucnt, ulist);
    nn_cold<<<512, 256, 0, stream>>>(src, tar, ucnt, ulist, umin);
    cold_sum<<<1, 1024, 0, stream>>>(ucnt, ulist, umin, partials);
    finish<<<1, 64, 0, stream>>>(partials, out);
}